// Round 8
// baseline (69.875 us; speedup 1.0000x reference)
//
#include <hip/hip_runtime.h>

#define DIM 16
#define NE 120            // edges in the Clements mesh for MODES=16
#define ITEMS 8           // batch items per block (2 waves; groups are wave-contained)
#define THREADS 128
#define UITEM 1032        // per-item LDS floats (1024 + 8 pad -> == 8 mod 32: group bank rotation)
#define LDS_FLOATS (ITEMS * UITEM)   // 8256 floats = 33024 B -> 4 blocks/CU

typedef float v2f __attribute__((ext_vector_type(2)));

// Per-item slot layout (no __syncthreads anywhere: every producer/consumer
// group is inside ONE wave, so s_waitcnt lgkmcnt(0) is sufficient):
//   [0,512)    U, column-major interleaved complex; column k = 128B at k*32 floats,
//              16B chunk q (elements i=2q,2q+1) stored at physical chunk q^(k&7).
//   [512,1024) phase P/B: cs-table record e at +4e = {cos t, sin t, cos p, sin p}
//              phase C/D: leftbuf; element (i,c) (float2) at +i*32 + 2*(c^i).

__global__ __launch_bounds__(THREADS, 2) void uparam_kernel(
    const float* __restrict__ params,
    const float* __restrict__ state_re,
    const float* __restrict__ state_im,
    float* __restrict__ out)
{
    __shared__ float lds[LDS_FLOATS];

    const int tid  = threadIdx.x;
    const int item = tid >> 4;
    const int c    = tid & 15;     // owns: U column c (B), left column c (C), out row c (D)
    const long b   = (long)blockIdx.x * ITEMS + item;

    float* slot = lds + item * UITEM;
    float* aux  = slot + 512;

    // ---------- Phase P: cooperative sincos table ---------------------------
    {
        const float* prow = params + b * (2 * NE);
        #pragma unroll
        for (int k = 0; k < 15; ++k) {
            const int a = k * 16 + c;
            float sv, cv;
            __sincosf(prow[a], &sv, &cv);
            const int e   = (a < NE) ? a : a - NE;
            const int off = (a < NE) ? 0 : 2;
            *(float2*)(aux + 4 * e + off) = make_float2(cv, sv);
        }
    }

    // ---------- rho column c -> registers (issued early, consumed in C) -----
    const float* rre = state_re + b * (DIM * DIM);
    const float* rim = state_im + b * (DIM * DIM);
    float prr[16], pri[16];
    #pragma unroll
    for (int k = 0; k < 16; ++k) { prr[k] = rre[k * 16 + c]; pri[k] = rim[k * 16 + c]; }

    asm volatile("s_waitcnt lgkmcnt(0)" ::: "memory");   // cs-table visible (same wave)

    // ---------- Phase B: build U column c in registers ----------------------
    v2f Uv[DIM];
    #pragma unroll
    for (int i = 0; i < DIM; ++i) Uv[i] = (v2f){ (i == c) ? 1.0f : 0.0f, 0.0f };

    #pragma unroll 1
    for (int l2 = 0; l2 < 8; ++l2) {
        const int eb = l2 * 15;
        #pragma unroll
        for (int j = 0; j < 15; ++j) {
            const int m = (j < 8) ? 2 * j : 2 * (j - 8) + 1;
            const int n = m + 1;
            const float4 cs = *(const float4*)(aux + 4 * (eb + j));
            const float ct = cs.x, st = cs.y, cp = cs.z, sp = cs.w;
            const v2f um = Uv[m], un = Uv[n];
            const v2f jm = { -um.y, um.x };      // i * um
            const v2f w  = cp * um + sp * jm;    // e^{i phi} * um
            Uv[m] = ct * w - st * un;
            Uv[n] = st * w + ct * un;
        }
    }

    // ---------- write U column c (chunk-swizzled, 8x b128, 2-way max) -------
    #pragma unroll
    for (int q = 0; q < 8; ++q) {
        const int qq = q ^ (c & 7);
        *(float4*)(slot + c * 32 + qq * 4) =
            make_float4(Uv[2*q].x, Uv[2*q].y, Uv[2*q+1].x, Uv[2*q+1].y);
    }

    asm volatile("s_waitcnt lgkmcnt(0)" ::: "memory");   // U visible (same wave)

    // ---------- Phase C: left[:,c] = sum_k U[:,k] * rho[k][c] ---------------
    v2f L[DIM];
    #pragma unroll
    for (int i = 0; i < DIM; ++i) L[i] = (v2f)(0.0f);

    #pragma unroll
    for (int k = 0; k < 16; ++k) {                // full unroll: prr/pri stay in regs
        const float* ucol = slot + k * 32;
        const int kx = k & 7;
        const float4 q0 = *(const float4*)(ucol + (0 ^ kx) * 4);
        const float4 q1 = *(const float4*)(ucol + (1 ^ kx) * 4);
        const float4 q2 = *(const float4*)(ucol + (2 ^ kx) * 4);
        const float4 q3 = *(const float4*)(ucol + (3 ^ kx) * 4);
        const float4 q4 = *(const float4*)(ucol + (4 ^ kx) * 4);
        const float4 q5 = *(const float4*)(ucol + (5 ^ kx) * 4);
        const float4 q6 = *(const float4*)(ucol + (6 ^ kx) * 4);
        const float4 q7 = *(const float4*)(ucol + (7 ^ kx) * 4);
        const float pr = prr[k], pi = pri[k];
        v2f u[16];
        u[0]=(v2f){q0.x,q0.y}; u[1]=(v2f){q0.z,q0.w}; u[2]=(v2f){q1.x,q1.y}; u[3]=(v2f){q1.z,q1.w};
        u[4]=(v2f){q2.x,q2.y}; u[5]=(v2f){q2.z,q2.w}; u[6]=(v2f){q3.x,q3.y}; u[7]=(v2f){q3.z,q3.w};
        u[8]=(v2f){q4.x,q4.y}; u[9]=(v2f){q4.z,q4.w}; u[10]=(v2f){q5.x,q5.y}; u[11]=(v2f){q5.z,q5.w};
        u[12]=(v2f){q6.x,q6.y}; u[13]=(v2f){q6.z,q6.w}; u[14]=(v2f){q7.x,q7.y}; u[15]=(v2f){q7.z,q7.w};
        #pragma unroll
        for (int i = 0; i < 16; ++i) {
            L[i] += u[i] * pr;
            L[i] += (v2f){ -u[i].y, u[i].x } * pi;   // + i*u*pi (VOP3P op_sel/neg foldable)
        }
    }

    // ---------- transpose left via LDS (XOR-swizzled float2, conflict-free) -
    #pragma unroll
    for (int i = 0; i < 16; ++i)
        *(v2f*)(aux + i * 32 + 2 * (c ^ i)) = L[i];

    asm volatile("s_waitcnt lgkmcnt(0)" ::: "memory");   // leftbuf visible (same wave)

    // ---------- Phase D: out[r][j] = sum_k left[r][k] * conj(U[j][k]), r=c --
    v2f acc[DIM];   // acc[j] = sum_k U[j][k] * conj(left[r][k]); out = conj(acc)
    #pragma unroll
    for (int j = 0; j < DIM; ++j) acc[j] = (v2f)(0.0f);

    #pragma unroll 4
    for (int k = 0; k < 16; ++k) {
        const v2f lk = *(const v2f*)(aux + c * 32 + 2 * (k ^ c));
        const float* ucol = slot + k * 32;
        const int kx = k & 7;
        const float4 q0 = *(const float4*)(ucol + (0 ^ kx) * 4);
        const float4 q1 = *(const float4*)(ucol + (1 ^ kx) * 4);
        const float4 q2 = *(const float4*)(ucol + (2 ^ kx) * 4);
        const float4 q3 = *(const float4*)(ucol + (3 ^ kx) * 4);
        const float4 q4 = *(const float4*)(ucol + (4 ^ kx) * 4);
        const float4 q5 = *(const float4*)(ucol + (5 ^ kx) * 4);
        const float4 q6 = *(const float4*)(ucol + (6 ^ kx) * 4);
        const float4 q7 = *(const float4*)(ucol + (7 ^ kx) * 4);
        v2f u[16];
        u[0]=(v2f){q0.x,q0.y}; u[1]=(v2f){q0.z,q0.w}; u[2]=(v2f){q1.x,q1.y}; u[3]=(v2f){q1.z,q1.w};
        u[4]=(v2f){q2.x,q2.y}; u[5]=(v2f){q2.z,q2.w}; u[6]=(v2f){q3.x,q3.y}; u[7]=(v2f){q3.z,q3.w};
        u[8]=(v2f){q4.x,q4.y}; u[9]=(v2f){q4.z,q4.w}; u[10]=(v2f){q5.x,q5.y}; u[11]=(v2f){q5.z,q5.w};
        u[12]=(v2f){q6.x,q6.y}; u[13]=(v2f){q6.z,q6.w}; u[14]=(v2f){q7.x,q7.y}; u[15]=(v2f){q7.z,q7.w};
        const float lr = lk.x, li = lk.y;
        #pragma unroll
        for (int j = 0; j < 16; ++j) {
            acc[j] += u[j] * lr;
            acc[j] += (v2f){ u[j].y, -u[j].x } * li;   // u*conj(l) accumulation
        }
    }

    // ---------- store: out row c (re plane, im plane) ------------------------
    float* outp = out + b * (2 * DIM * DIM) + c * DIM;
    #pragma unroll
    for (int q = 0; q < 4; ++q) {
        *(float4*)(outp + 4 * q) =
            make_float4(acc[4*q].x, acc[4*q+1].x, acc[4*q+2].x, acc[4*q+3].x);
        *(float4*)(outp + DIM * DIM + 4 * q) =
            make_float4(-acc[4*q].y, -acc[4*q+1].y, -acc[4*q+2].y, -acc[4*q+3].y);
    }
}

extern "C" void kernel_launch(void* const* d_in, const int* in_sizes, int n_in,
                              void* d_out, int out_size, void* d_ws, size_t ws_size,
                              hipStream_t stream) {
    const float* params   = (const float*)d_in[0];
    const float* state_re = (const float*)d_in[1];
    const float* state_im = (const float*)d_in[2];
    // d_in[3] = targets; structure is the fixed Clements mesh, derived in-kernel.
    float* out = (float*)d_out;

    const int batch = in_sizes[0] / (2 * NE);   // 32768
    dim3 grid(batch / ITEMS);                   // 4096 blocks
    uparam_kernel<<<grid, THREADS, 0, stream>>>(params, state_re, state_im, out);
}